// Round 10
// baseline (351.462 us; speedup 1.0000x reference)
//
#include <hip/hip_runtime.h>
#include <hip/hip_bf16.h>
#include <stdint.h>

typedef unsigned short u16;
typedef __bf16 bf16_t;
typedef bf16_t bf16x8 __attribute__((ext_vector_type(8)));
typedef u16    u16x8  __attribute__((ext_vector_type(8)));
typedef u16    u16x4  __attribute__((ext_vector_type(4)));
typedef float  f32x4  __attribute__((ext_vector_type(4)));

#define BSZ    256
#define NATOMS 128
#define INF    128
#define HH     256
#define H3     768
#define MAXV   6
#define OUTF   256
#define KFC    (HH * MAXV)      // 1536
#define PLANE  8388608          // u16 elems per xp2 gate plane
#define HAP    264              // hA row pitch (u16)

__device__ __forceinline__ u16 f2bf(float f) {
  union { float f; unsigned u; } v; v.f = f;
  unsigned u = v.u;
  unsigned r = (u + 0x7FFFu + ((u >> 16) & 1u)) >> 16;  // RNE
  return (u16)r;
}
__device__ __forceinline__ float bf2f(u16 h) {
  union { unsigned u; float f; } v; v.u = ((unsigned)h) << 16;
  return v.f;
}
__device__ __forceinline__ f32x4 mfma_bf16(u16x8 a, u16x8 b, f32x4 c) {
  return __builtin_amdgcn_mfma_f32_16x16x32_bf16(
      __builtin_bit_cast(bf16x8, a), __builtin_bit_cast(bf16x8, b), c, 0, 0, 0);
}
__device__ __forceinline__ float sel4(float a0, float a1, float a2, float a3, int q) {
  float t01 = (q & 1) ? a1 : a0;
  float t23 = (q & 1) ? a3 : a2;
  return (q & 2) ? t23 : t01;
}

// ---------------- prep: x, W_ih, W_hh, W_fc fp32 -> bf16 (float4 vectorized) --
#define NX4   1048576
#define C1    1048576
#define C2    1073152
#define C3    1122304
#define C4    1220608
__global__ void k_prep4(const float* __restrict__ x, const float* __restrict__ wih,
                        const float* __restrict__ whh, const float* __restrict__ wfc,
                        u16* __restrict__ xb, u16* __restrict__ wihb,
                        u16* __restrict__ whhb, u16* __restrict__ wfcb) {
  int i = blockIdx.x * 256 + threadIdx.x;
  const float* src; u16* dst; int j;
  if (i < C1)      { src = x;   dst = xb;   j = i; }
  else if (i < C2) { src = wih; dst = wihb; j = i - C1; }
  else if (i < C3) { src = whh; dst = whhb; j = i - C2; }
  else             { src = wfc; dst = wfcb; j = i - C3; }
  f32x4 v = *(const f32x4*)(src + (size_t)j * 4);
  u16x4 o;
#pragma unroll
  for (int k = 0; k < 4; k++) o[k] = f2bf(v[k]);
  *(u16x4*)(dst + (size_t)j * 4) = o;
}

// ---------------- stage 1: xp2 = x @ W_ih^T + biases (128x128 tile, BK=128) --
__global__ __launch_bounds__(256) void k_xproj(const u16* __restrict__ X,
                                               const u16* __restrict__ W,
                                               const float* __restrict__ bias,
                                               const float* __restrict__ bhh,
                                               u16* __restrict__ out) {
  __shared__ __align__(16) u16 As[128][136];
  __shared__ __align__(16) u16 Bs[128][136];
  const int tid = threadIdx.x, lane = tid & 63, wid = tid >> 6;
  const int c16 = lane & 15, quad = lane >> 4;
  const int wm = (wid & 1) * 64, wn = (wid >> 1) * 64;
  const int bg = blockIdx.x >> 2, tg = blockIdx.x & 3;
  const int n0 = blockIdx.y * 128;

#pragma unroll
  for (int j = 0; j < 8; j++) {
    const int u = tid + j * 256, row = u >> 4, ch = u & 15;
    const int b = bg * 4 + (row & 3), t = tg * 32 + (row >> 2);
    *(u16x8*)&As[row][ch * 8] =
        *(const u16x8*)(X + ((size_t)b * 16384 + t * 128 + ch * 8));
    *(u16x8*)&Bs[row][ch * 8] =
        *(const u16x8*)(W + ((size_t)(n0 + row) * 128 + ch * 8));
  }
  __syncthreads();

  const f32x4 zero = {0.f, 0.f, 0.f, 0.f};
  f32x4 acc[4][4];
#pragma unroll
  for (int mi = 0; mi < 4; mi++)
#pragma unroll
    for (int ni = 0; ni < 4; ni++) acc[mi][ni] = zero;

#pragma unroll
  for (int kt = 0; kt < 4; kt++) {
    u16x8 af[4], bf[4];
#pragma unroll
    for (int mi = 0; mi < 4; mi++)
      af[mi] = *(const u16x8*)&As[wm + mi * 16 + c16][kt * 32 + quad * 8];
#pragma unroll
    for (int ni = 0; ni < 4; ni++)
      bf[ni] = *(const u16x8*)&Bs[wn + ni * 16 + c16][kt * 32 + quad * 8];
#pragma unroll
    for (int mi = 0; mi < 4; mi++)
#pragma unroll
      for (int ni = 0; ni < 4; ni++)
        acc[mi][ni] = mfma_bf16(af[mi], bf[ni], acc[mi][ni]);
  }

  const int bb = bg >> 2, mbh = bg & 3;
#pragma unroll
  for (int ni = 0; ni < 4; ni++) {
    const int n = n0 + wn + ni * 16 + c16;
    const int g = n >> 8, ww = (n >> 5) & 7, pp = (n >> 4) & 1, cc = n & 15;
    const float badd = bias[n] + (g < 2 ? bhh[n] : 0.f);
    u16* plane = out + (size_t)g * PLANE;
#pragma unroll
    for (int mi = 0; mi < 4; mi++) {
      const int t = tg * 32 + (wm >> 2) + mi * 4 + quad;
      u16x4 sv;
#pragma unroll
      for (int r_ = 0; r_ < 4; r_++) sv[r_] = f2bf(acc[mi][ni][r_] + badd);
      *(u16x4*)(plane + (((size_t)((bb * 128 + t) * 8 + ww)) << 9) +
                (mbh * 16 + cc) * 8 + pp * 4) = sv;
    }
  }
}

// ---------------- stage 2: GRU recurrence (R1-verified loop, new preamble) --
// R16 (resubmitted after R9 infra failure): the ONLY change vs the verified
// 338-us build is the wf load preamble.
// Old: 96 loads all issued, then 96 AGPR pins -> compiler round-trips each
// load through scarce VGPRs SERIALLY (~450 cyc x 96 = ~18 us, confirmed by
// R5 probe totals: p1+p2 = 2x(18+52) us).
// New: 8 groups of 12 loads -> 12 loads overlap in flight (48 VGPR temps),
// then pin that group to AGPRs. Expected preamble ~2 us.
// In-loop schedule BYTE-IDENTICAL (regalloc cliff: R13's in-loop edit = -43%).
__global__ void __attribute__((amdgpu_flat_work_group_size(256, 256),
                               amdgpu_waves_per_eu(1, 1)))
k_gru(const u16* __restrict__ Whh, const float* __restrict__ bhh,
      const u16* __restrict__ xp2, u16* __restrict__ rnn) {
  __shared__ __align__(16) u16 hA[2][4 * HAP];
  const int tid = threadIdx.x, lane = tid & 63, w = tid >> 6;
  const int c = lane & 15, q = lane >> 4;
  const int b0 = blockIdx.x * 4;
  const int bb = blockIdx.x >> 2;
  const int Lq = (blockIdx.x & 3) * 16 + c;

  for (int i = tid; i < 2 * 4 * HAP; i += 256) ((u16*)hA)[i] = 0;

  u16x8 wf[12][8];
#pragma unroll
  for (int kt = 0; kt < 8; kt++) {
#pragma unroll
    for (int nt = 0; nt < 12; nt++) {
      const int n = (nt >> 2) * 256 + w * 64 + (nt & 3) * 16 + c;
      wf[nt][kt] = *(const u16x8*)(Whh + (size_t)n * HH + kt * 32 + q * 8);
    }
#pragma unroll
    for (int nt = 0; nt < 12; nt++) asm volatile("" : "+a"(wf[nt][kt]));
  }

  const int col = w * 64 + q * 16 + c;
  const float bhhn = bhh[512 + col];
  float hreg[4] = {0.f, 0.f, 0.f, 0.f};

  const u16* gbase = xp2 + ((size_t)(bb * 128) * 8 + (w * 2 + (q >> 1))) * 512 +
                     (size_t)Lq * 8 + (q & 1) * 4;
  const int sl = lane & 31;
  u16* rnn_base = rnn + ((size_t)(b0 + w) * NATOMS) * HH + sl * 8;

  // prefetch ring, depth 2: xg0 holds even-t data, xg1 odd-t data
  u16x4 xg0[3], xg1[3];
#pragma unroll
  for (int g = 0; g < 3; g++) xg0[g] = *(const u16x4*)(gbase + (size_t)g * PLANE);
#pragma unroll
  for (int g = 0; g < 3; g++) xg1[g] = *(const u16x4*)(gbase + 4096 + (size_t)g * PLANE);
  const u16* gpre = gbase + 2 * 4096;

  // hA zero-init visible to all waves; wf/xg loads may stay in flight
  asm volatile("s_waitcnt lgkmcnt(0)\n\ts_barrier" ::: "memory");

  const f32x4 zero4 = {0.f, 0.f, 0.f, 0.f};

  auto step = [&](const int t, u16x4 (&xgc)[3]) {
    const u16* hc = hA[t & 1];
    u16* hnx = hA[(t + 1) & 1];

    if (t && lane < 32) {
      const u16x8 hv8 = *(const u16x8*)&hc[w * HAP + sl * 8];
      *(u16x8*)(rnn_base + (size_t)(t - 1) * HH) = hv8;
    }

    u16x4 xg[3];
#pragma unroll
    for (int g = 0; g < 3; g++) xg[g] = xgc[g];
    if (t < NATOMS - 2) {
#pragma unroll
      for (int g = 0; g < 3; g++)
        xgc[g] = *(const u16x4*)(gpre + (size_t)g * PLANE);
    }

    // 2-stage ds_read pipeline; kt=0 MFMA consumes zero4 as C (no acc init)
    f32x4 acc[12];
    u16x8 a0 = *(const u16x8*)&hc[(c & 3) * HAP + q * 8];
#pragma unroll
    for (int kt = 0; kt < 8; kt++) {
      u16x8 a1;
      if (kt < 7)
        a1 = *(const u16x8*)&hc[(c & 3) * HAP + (kt + 1) * 32 + q * 8];
      if (kt == 0) {
#pragma unroll
        for (int nt = 0; nt < 12; nt++) acc[nt] = mfma_bf16(a0, wf[nt][0], zero4);
      } else {
#pragma unroll
        for (int nt = 0; nt < 12; nt++) acc[nt] = mfma_bf16(a0, wf[nt][kt], acc[nt]);
      }
      a0 = a1;
    }

#pragma unroll
    for (int r_ = 0; r_ < 4; r_++) {
      const float Ar = sel4(acc[0][r_], acc[1][r_], acc[2][r_], acc[3][r_], q);
      const float Az = sel4(acc[4][r_], acc[5][r_], acc[6][r_], acc[7][r_], q);
      const float An = sel4(acc[8][r_], acc[9][r_], acc[10][r_], acc[11][r_], q);
      const float ar = Ar + bf2f(xg[0][r_]);
      const float az = Az + bf2f(xg[1][r_]);
      const float hn = An + bhhn;
      const float xn = bf2f(xg[2][r_]);
      const float rr = 1.f / (1.f + __expf(-ar));
      const float zz = 1.f / (1.f + __expf(-az));
      const float e  = __expf(2.f * (xn + rr * hn));
      const float nn = 1.f - 2.f / (e + 1.f);
      const float hv = nn + zz * (hreg[r_] - nn);
      hreg[r_] = hv;
      hnx[r_ * HAP + col] = f2bf(hv);
    }

    // LDS-only barrier: own ds_writes retired, then rendezvous.
    // Global loads/stores deliberately left in flight (no vmcnt drain).
    asm volatile("s_waitcnt lgkmcnt(0)\n\ts_barrier" ::: "memory");
  };

#pragma unroll 1
  for (int tt = 0; tt < NATOMS; tt += 2) {
    step(tt, xg0);
    gpre += 4096;
    step(tt + 1, xg1);
    gpre += 4096;
  }

  if (lane < 32) {
    const u16x8 hv8 = *(const u16x8*)&hA[0][w * HAP + sl * 8];
    *(u16x8*)(rnn_base + (size_t)(NATOMS - 1) * HH) = hv8;
  }
}

// ---------------- stage 3: out = leaky(gather(rnn) @ W_fc^T + b_fc) ---------
// R10 double-buffered version (harness-verified in R4/R5/R6/R8).
__global__ __launch_bounds__(256) void k_fc(const u16* __restrict__ rnn,
                                            const int* __restrict__ bonded,
                                            const u16* __restrict__ W,
                                            const float* __restrict__ bias,
                                            float* __restrict__ out) {
  __shared__ __align__(16) u16 As[2][128][72];
  __shared__ __align__(16) u16 Bs[2][128][72];
  __shared__ int ic[128][6];
  const int tid = threadIdx.x, lane = tid & 63, wid = tid >> 6;
  const int c16 = lane & 15, quad = lane >> 4;
  const int wNm = (wid & 1) * 64;
  const int wNa = (wid >> 1) * 64;
  const int bx = blockIdx.x, n0 = blockIdx.y * 128;
  const int srow = tid >> 3, sch = tid & 7;

  for (int u = tid; u < 768; u += 256) {
    const int v = u >> 7, row = u & 127;
    ic[row][v] = bonded[(size_t)(bx * 128 + row) * MAXV + v];
  }
  __syncthreads();

  u16x8 ra[4], rb[4];
#define STAGE_LOAD(IT)                                                         \
  {                                                                            \
    const int kk_ = (IT) * 64, v_ = kk_ >> 8, kr_ = kk_ & 255;                 \
    _Pragma("unroll")                                                          \
    for (int j = 0; j < 4; j++) {                                              \
      const int row_ = srow + j * 32;                                          \
      const int idx_ = ic[row_][v_];                                           \
      ra[j] = *(const u16x8*)(rnn + ((size_t)(bx * 128 + idx_)) * HH + kr_ +   \
                              sch * 8);                                        \
      rb[j] = *(const u16x8*)(W + (size_t)(n0 + row_) * KFC + kk_ + sch * 8);  \
    }                                                                          \
  }
#define STAGE_WRITE(B_)                                                        \
  {                                                                            \
    _Pragma("unroll")                                                          \
    for (int j = 0; j < 4; j++) {                                              \
      const int row_ = srow + j * 32;                                          \
      *(u16x8*)&As[B_][row_][sch * 8] = ra[j];                                 \
      *(u16x8*)&Bs[B_][row_][sch * 8] = rb[j];                                 \
    }                                                                          \
  }

  STAGE_LOAD(0);
  STAGE_WRITE(0);
  __syncthreads();

  const f32x4 zero = {0.f, 0.f, 0.f, 0.f};
  f32x4 acc[4][4];
#pragma unroll
  for (int mi = 0; mi < 4; mi++)
#pragma unroll
    for (int ni = 0; ni < 4; ni++) acc[mi][ni] = zero;

#pragma unroll 1
  for (int it = 0; it < 24; it++) {
    const int cur = it & 1;
    if (it < 23) STAGE_LOAD(it + 1);
#pragma unroll
    for (int kt = 0; kt < 2; kt++) {
      u16x8 aw[4], ba[4];
#pragma unroll
      for (int mi = 0; mi < 4; mi++)
        aw[mi] = *(const u16x8*)&Bs[cur][wNm + mi * 16 + c16][kt * 32 + quad * 8];
#pragma unroll
      for (int ni = 0; ni < 4; ni++)
        ba[ni] = *(const u16x8*)&As[cur][wNa + ni * 16 + c16][kt * 32 + quad * 8];
#pragma unroll
      for (int mi = 0; mi < 4; mi++)
#pragma unroll
        for (int ni = 0; ni < 4; ni++)
          acc[mi][ni] = mfma_bf16(aw[mi], ba[ni], acc[mi][ni]);
    }
    if (it < 23) STAGE_WRITE(cur ^ 1);
    __syncthreads();
  }

#pragma unroll
  for (int mi = 0; mi < 4; mi++) {
    const int n = n0 + wNm + mi * 16 + quad * 4;
    const f32x4 bv = *(const f32x4*)(bias + n);
#pragma unroll
    for (int ni = 0; ni < 4; ni++) {
      const int mm = bx * 128 + wNa + ni * 16 + c16;
      f32x4 vv;
#pragma unroll
      for (int r_ = 0; r_ < 4; r_++) {
        const float t = acc[mi][ni][r_] + bv[r_];
        vv[r_] = t >= 0.f ? t : 0.1f * t;
      }
      *(f32x4*)(out + (size_t)mm * OUTF + n) = vv;
    }
  }
}

extern "C" void kernel_launch(void* const* d_in, const int* in_sizes, int n_in,
                              void* d_out, int out_size, void* d_ws, size_t ws_size,
                              hipStream_t stream) {
  const float* x      = (const float*)d_in[0];
  const int*   bonded = (const int*)d_in[1];
  const float* Wih    = (const float*)d_in[2];
  const float* Whh    = (const float*)d_in[3];
  const float* bih    = (const float*)d_in[4];
  const float* bhh    = (const float*)d_in[5];
  const float* Wfc    = (const float*)d_in[6];
  const float* bfc    = (const float*)d_in[7];
  float* out = (float*)d_out;

  char* ws = (char*)d_ws;
  u16* xp2  = (u16*)(ws);                       // 50,331,648 B
  u16* rnn  = (u16*)(ws + 50331648);            // 16,777,216 B
  u16* whhb = (u16*)(ws + 67108864);            //    393,216 B
  u16* wfcb = (u16*)(ws + 67502080);            //    786,432 B
  u16* xb   = (u16*)(ws + 68288512);            //  8,388,608 B
  u16* wihb = (u16*)(ws + 76677120);            //    196,608 B

  k_prep4<<<C4 / 256, 256, 0, stream>>>(x, Wih, Whh, Wfc, xb, wihb, whhb, wfcb);
  k_xproj<<<dim3(256, 6), 256, 0, stream>>>(xb, wihb, bih, bhh, xp2);
  k_gru<<<64, 256, 0, stream>>>(whhb, bhh, xp2, rnn);
  k_fc<<<dim3(256, 2), 256, 0, stream>>>(rnn, bonded, wfcb, bfc, out);
}

// Round 11
// 337.396 us; speedup vs baseline: 1.0417x; 1.0417x over previous
//
#include <hip/hip_runtime.h>
#include <hip/hip_bf16.h>
#include <stdint.h>

typedef unsigned short u16;
typedef __bf16 bf16_t;
typedef bf16_t bf16x8 __attribute__((ext_vector_type(8)));
typedef u16    u16x8  __attribute__((ext_vector_type(8)));
typedef u16    u16x4  __attribute__((ext_vector_type(4)));
typedef float  f32x4  __attribute__((ext_vector_type(4)));

#define BSZ    256
#define NATOMS 128
#define INF    128
#define HH     256
#define H3     768
#define MAXV   6
#define OUTF   256
#define KFC    (HH * MAXV)      // 1536
#define PLANE  8388608          // u16 elems per xp2 gate plane
#define HAP    264              // hA row pitch (u16)

__device__ __forceinline__ u16 f2bf(float f) {
  union { float f; unsigned u; } v; v.f = f;
  unsigned u = v.u;
  unsigned r = (u + 0x7FFFu + ((u >> 16) & 1u)) >> 16;  // RNE
  return (u16)r;
}
__device__ __forceinline__ float bf2f(u16 h) {
  union { unsigned u; float f; } v; v.u = ((unsigned)h) << 16;
  return v.f;
}
__device__ __forceinline__ f32x4 mfma_bf16(u16x8 a, u16x8 b, f32x4 c) {
  return __builtin_amdgcn_mfma_f32_16x16x32_bf16(
      __builtin_bit_cast(bf16x8, a), __builtin_bit_cast(bf16x8, b), c, 0, 0, 0);
}
__device__ __forceinline__ float sel4(float a0, float a1, float a2, float a3, int q) {
  float t01 = (q & 1) ? a1 : a0;
  float t23 = (q & 1) ? a3 : a2;
  return (q & 2) ? t23 : t01;
}

// ---------------- stage 1: xp2 = x @ W_ih^T + biases (128x128 tile, BK=128) --
// R17: k_prep4 is ELIMINATED. x and W_ih are converted fp32->bf16 inline
// during LDS staging (saves the 16MB xb write + 16MB xb read + one launch).
// whh/wfc conversion runs as a side-task of the blockIdx.y==0 blocks (256
// blocks x 256 thr over 147,456 f32x4 -> ~3 iters each); k_gru/k_fc launch
// after ALL xproj blocks by stream order, so the dependency is safe.
#define NWHH4 49152    // whh f32x4 count (768*256/4)
#define NCVT4 147456   // whh + wfc f32x4 count
__global__ __launch_bounds__(256) void k_xproj(const float* __restrict__ X,
                                               const float* __restrict__ W,
                                               const float* __restrict__ bias,
                                               const float* __restrict__ bhh,
                                               u16* __restrict__ out,
                                               const float* __restrict__ whh,
                                               u16* __restrict__ whhb,
                                               const float* __restrict__ wfc,
                                               u16* __restrict__ wfcb) {
  __shared__ __align__(16) u16 As[128][136];
  __shared__ __align__(16) u16 Bs[128][136];
  const int tid = threadIdx.x, lane = tid & 63, wid = tid >> 6;
  const int c16 = lane & 15, quad = lane >> 4;
  const int wm = (wid & 1) * 64, wn = (wid >> 1) * 64;
  const int bg = blockIdx.x >> 2, tg = blockIdx.x & 3;
  const int n0 = blockIdx.y * 128;

  // side-task: convert whh + wfc to bf16 (y==0 blocks only)
  if (blockIdx.y == 0) {
    for (int i = blockIdx.x * 256 + tid; i < NCVT4; i += 256 * 256) {
      const float* s;
      u16* d;
      int j;
      if (i < NWHH4) { s = whh; d = whhb; j = i; }
      else           { s = wfc; d = wfcb; j = i - NWHH4; }
      f32x4 v = *(const f32x4*)(s + (size_t)j * 4);
      u16x4 o;
#pragma unroll
      for (int k = 0; k < 4; k++) o[k] = f2bf(v[k]);
      *(u16x4*)(d + (size_t)j * 4) = o;
    }
  }

  // staging with inline fp32->bf16 conversion
#pragma unroll
  for (int j = 0; j < 8; j++) {
    const int u = tid + j * 256, row = u >> 4, ch = u & 15;
    const int b = bg * 4 + (row & 3), t = tg * 32 + (row >> 2);
    const float* xs = X + ((size_t)b * 16384 + t * 128 + ch * 8);
    const f32x4 v0 = *(const f32x4*)(xs);
    const f32x4 v1 = *(const f32x4*)(xs + 4);
    u16x8 xa;
#pragma unroll
    for (int k = 0; k < 4; k++) { xa[k] = f2bf(v0[k]); xa[4 + k] = f2bf(v1[k]); }
    *(u16x8*)&As[row][ch * 8] = xa;

    const float* wsrc = W + ((size_t)(n0 + row) * 128 + ch * 8);
    const f32x4 w0 = *(const f32x4*)(wsrc);
    const f32x4 w1 = *(const f32x4*)(wsrc + 4);
    u16x8 wb;
#pragma unroll
    for (int k = 0; k < 4; k++) { wb[k] = f2bf(w0[k]); wb[4 + k] = f2bf(w1[k]); }
    *(u16x8*)&Bs[row][ch * 8] = wb;
  }
  __syncthreads();

  const f32x4 zero = {0.f, 0.f, 0.f, 0.f};
  f32x4 acc[4][4];
#pragma unroll
  for (int mi = 0; mi < 4; mi++)
#pragma unroll
    for (int ni = 0; ni < 4; ni++) acc[mi][ni] = zero;

#pragma unroll
  for (int kt = 0; kt < 4; kt++) {
    u16x8 af[4], bf[4];
#pragma unroll
    for (int mi = 0; mi < 4; mi++)
      af[mi] = *(const u16x8*)&As[wm + mi * 16 + c16][kt * 32 + quad * 8];
#pragma unroll
    for (int ni = 0; ni < 4; ni++)
      bf[ni] = *(const u16x8*)&Bs[wn + ni * 16 + c16][kt * 32 + quad * 8];
#pragma unroll
    for (int mi = 0; mi < 4; mi++)
#pragma unroll
      for (int ni = 0; ni < 4; ni++)
        acc[mi][ni] = mfma_bf16(af[mi], bf[ni], acc[mi][ni]);
  }

  const int bb = bg >> 2, mbh = bg & 3;
#pragma unroll
  for (int ni = 0; ni < 4; ni++) {
    const int n = n0 + wn + ni * 16 + c16;
    const int g = n >> 8, ww = (n >> 5) & 7, pp = (n >> 4) & 1, cc = n & 15;
    const float badd = bias[n] + (g < 2 ? bhh[n] : 0.f);
    u16* plane = out + (size_t)g * PLANE;
#pragma unroll
    for (int mi = 0; mi < 4; mi++) {
      const int t = tg * 32 + (wm >> 2) + mi * 4 + quad;
      u16x4 sv;
#pragma unroll
      for (int r_ = 0; r_ < 4; r_++) sv[r_] = f2bf(acc[mi][ni][r_] + badd);
      *(u16x4*)(plane + (((size_t)((bb * 128 + t) * 8 + ww)) << 9) +
                (mbh * 16 + cc) * 8 + pp * 4) = sv;
    }
  }
}

// ---------------- stage 2: GRU recurrence (R8-verified, byte-identical) -----
// The 209.3-us equilibrium. Do NOT perturb: preamble regroup (R16) = -14us,
// in-loop store move (R13) = -43%, LDS W-stream (R12) = -7%. All reverted.
__global__ void __attribute__((amdgpu_flat_work_group_size(256, 256),
                               amdgpu_waves_per_eu(1, 1)))
k_gru(const u16* __restrict__ Whh, const float* __restrict__ bhh,
      const u16* __restrict__ xp2, u16* __restrict__ rnn) {
  __shared__ __align__(16) u16 hA[2][4 * HAP];
  const int tid = threadIdx.x, lane = tid & 63, w = tid >> 6;
  const int c = lane & 15, q = lane >> 4;
  const int b0 = blockIdx.x * 4;
  const int bb = blockIdx.x >> 2;
  const int Lq = (blockIdx.x & 3) * 16 + c;

  for (int i = tid; i < 2 * 4 * HAP; i += 256) ((u16*)hA)[i] = 0;

  u16x8 wf[12][8];
#pragma unroll
  for (int nt = 0; nt < 12; nt++)
#pragma unroll
    for (int kt = 0; kt < 8; kt++) {
      const int n = (nt >> 2) * 256 + w * 64 + (nt & 3) * 16 + c;
      wf[nt][kt] = *(const u16x8*)(Whh + (size_t)n * HH + kt * 32 + q * 8);
    }
#pragma unroll
  for (int nt = 0; nt < 12; nt++)
#pragma unroll
    for (int kt = 0; kt < 8; kt++) asm volatile("" : "+a"(wf[nt][kt]));

  const int col = w * 64 + q * 16 + c;
  const float bhhn = bhh[512 + col];
  float hreg[4] = {0.f, 0.f, 0.f, 0.f};

  const u16* gbase = xp2 + ((size_t)(bb * 128) * 8 + (w * 2 + (q >> 1))) * 512 +
                     (size_t)Lq * 8 + (q & 1) * 4;
  const int sl = lane & 31;
  u16* rnn_base = rnn + ((size_t)(b0 + w) * NATOMS) * HH + sl * 8;

  // prefetch ring, depth 2: xg0 holds even-t data, xg1 odd-t data
  u16x4 xg0[3], xg1[3];
#pragma unroll
  for (int g = 0; g < 3; g++) xg0[g] = *(const u16x4*)(gbase + (size_t)g * PLANE);
#pragma unroll
  for (int g = 0; g < 3; g++) xg1[g] = *(const u16x4*)(gbase + 4096 + (size_t)g * PLANE);
  const u16* gpre = gbase + 2 * 4096;

  // hA zero-init visible to all waves; wf/xg loads may stay in flight
  asm volatile("s_waitcnt lgkmcnt(0)\n\ts_barrier" ::: "memory");

  const f32x4 zero4 = {0.f, 0.f, 0.f, 0.f};

  auto step = [&](const int t, u16x4 (&xgc)[3]) {
    const u16* hc = hA[t & 1];
    u16* hnx = hA[(t + 1) & 1];

    if (t && lane < 32) {
      const u16x8 hv8 = *(const u16x8*)&hc[w * HAP + sl * 8];
      *(u16x8*)(rnn_base + (size_t)(t - 1) * HH) = hv8;
    }

    u16x4 xg[3];
#pragma unroll
    for (int g = 0; g < 3; g++) xg[g] = xgc[g];
    if (t < NATOMS - 2) {
#pragma unroll
      for (int g = 0; g < 3; g++)
        xgc[g] = *(const u16x4*)(gpre + (size_t)g * PLANE);
    }

    // 2-stage ds_read pipeline; kt=0 MFMA consumes zero4 as C (no acc init)
    f32x4 acc[12];
    u16x8 a0 = *(const u16x8*)&hc[(c & 3) * HAP + q * 8];
#pragma unroll
    for (int kt = 0; kt < 8; kt++) {
      u16x8 a1;
      if (kt < 7)
        a1 = *(const u16x8*)&hc[(c & 3) * HAP + (kt + 1) * 32 + q * 8];
      if (kt == 0) {
#pragma unroll
        for (int nt = 0; nt < 12; nt++) acc[nt] = mfma_bf16(a0, wf[nt][0], zero4);
      } else {
#pragma unroll
        for (int nt = 0; nt < 12; nt++) acc[nt] = mfma_bf16(a0, wf[nt][kt], acc[nt]);
      }
      a0 = a1;
    }

#pragma unroll
    for (int r_ = 0; r_ < 4; r_++) {
      const float Ar = sel4(acc[0][r_], acc[1][r_], acc[2][r_], acc[3][r_], q);
      const float Az = sel4(acc[4][r_], acc[5][r_], acc[6][r_], acc[7][r_], q);
      const float An = sel4(acc[8][r_], acc[9][r_], acc[10][r_], acc[11][r_], q);
      const float ar = Ar + bf2f(xg[0][r_]);
      const float az = Az + bf2f(xg[1][r_]);
      const float hn = An + bhhn;
      const float xn = bf2f(xg[2][r_]);
      const float rr = 1.f / (1.f + __expf(-ar));
      const float zz = 1.f / (1.f + __expf(-az));
      const float e  = __expf(2.f * (xn + rr * hn));
      const float nn = 1.f - 2.f / (e + 1.f);
      const float hv = nn + zz * (hreg[r_] - nn);
      hreg[r_] = hv;
      hnx[r_ * HAP + col] = f2bf(hv);
    }

    // LDS-only barrier: own ds_writes retired, then rendezvous.
    // Global loads/stores deliberately left in flight (no vmcnt drain).
    asm volatile("s_waitcnt lgkmcnt(0)\n\ts_barrier" ::: "memory");
  };

#pragma unroll 1
  for (int tt = 0; tt < NATOMS; tt += 2) {
    step(tt, xg0);
    gpre += 4096;
    step(tt + 1, xg1);
    gpre += 4096;
  }

  if (lane < 32) {
    const u16x8 hv8 = *(const u16x8*)&hA[0][w * HAP + sl * 8];
    *(u16x8*)(rnn_base + (size_t)(NATOMS - 1) * HH) = hv8;
  }
}

// ---------------- stage 3: out = leaky(gather(rnn) @ W_fc^T + b_fc) ---------
// R10 double-buffered version (harness-verified in R4/R5/R6/R8/R10).
__global__ __launch_bounds__(256) void k_fc(const u16* __restrict__ rnn,
                                            const int* __restrict__ bonded,
                                            const u16* __restrict__ W,
                                            const float* __restrict__ bias,
                                            float* __restrict__ out) {
  __shared__ __align__(16) u16 As[2][128][72];
  __shared__ __align__(16) u16 Bs[2][128][72];
  __shared__ int ic[128][6];
  const int tid = threadIdx.x, lane = tid & 63, wid = tid >> 6;
  const int c16 = lane & 15, quad = lane >> 4;
  const int wNm = (wid & 1) * 64;
  const int wNa = (wid >> 1) * 64;
  const int bx = blockIdx.x, n0 = blockIdx.y * 128;
  const int srow = tid >> 3, sch = tid & 7;

  for (int u = tid; u < 768; u += 256) {
    const int v = u >> 7, row = u & 127;
    ic[row][v] = bonded[(size_t)(bx * 128 + row) * MAXV + v];
  }
  __syncthreads();

  u16x8 ra[4], rb[4];
#define STAGE_LOAD(IT)                                                         \
  {                                                                            \
    const int kk_ = (IT) * 64, v_ = kk_ >> 8, kr_ = kk_ & 255;                 \
    _Pragma("unroll")                                                          \
    for (int j = 0; j < 4; j++) {                                              \
      const int row_ = srow + j * 32;                                          \
      const int idx_ = ic[row_][v_];                                           \
      ra[j] = *(const u16x8*)(rnn + ((size_t)(bx * 128 + idx_)) * HH + kr_ +   \
                              sch * 8);                                        \
      rb[j] = *(const u16x8*)(W + (size_t)(n0 + row_) * KFC + kk_ + sch * 8);  \
    }                                                                          \
  }
#define STAGE_WRITE(B_)                                                        \
  {                                                                            \
    _Pragma("unroll")                                                          \
    for (int j = 0; j < 4; j++) {                                              \
      const int row_ = srow + j * 32;                                          \
      *(u16x8*)&As[B_][row_][sch * 8] = ra[j];                                 \
      *(u16x8*)&Bs[B_][row_][sch * 8] = rb[j];                                 \
    }                                                                          \
  }

  STAGE_LOAD(0);
  STAGE_WRITE(0);
  __syncthreads();

  const f32x4 zero = {0.f, 0.f, 0.f, 0.f};
  f32x4 acc[4][4];
#pragma unroll
  for (int mi = 0; mi < 4; mi++)
#pragma unroll
    for (int ni = 0; ni < 4; ni++) acc[mi][ni] = zero;

#pragma unroll 1
  for (int it = 0; it < 24; it++) {
    const int cur = it & 1;
    if (it < 23) STAGE_LOAD(it + 1);
#pragma unroll
    for (int kt = 0; kt < 2; kt++) {
      u16x8 aw[4], ba[4];
#pragma unroll
      for (int mi = 0; mi < 4; mi++)
        aw[mi] = *(const u16x8*)&Bs[cur][wNm + mi * 16 + c16][kt * 32 + quad * 8];
#pragma unroll
      for (int ni = 0; ni < 4; ni++)
        ba[ni] = *(const u16x8*)&As[cur][wNa + ni * 16 + c16][kt * 32 + quad * 8];
#pragma unroll
      for (int mi = 0; mi < 4; mi++)
#pragma unroll
        for (int ni = 0; ni < 4; ni++)
          acc[mi][ni] = mfma_bf16(aw[mi], ba[ni], acc[mi][ni]);
    }
    if (it < 23) STAGE_WRITE(cur ^ 1);
    __syncthreads();
  }

#pragma unroll
  for (int mi = 0; mi < 4; mi++) {
    const int n = n0 + wNm + mi * 16 + quad * 4;
    const f32x4 bv = *(const f32x4*)(bias + n);
#pragma unroll
    for (int ni = 0; ni < 4; ni++) {
      const int mm = bx * 128 + wNa + ni * 16 + c16;
      f32x4 vv;
#pragma unroll
      for (int r_ = 0; r_ < 4; r_++) {
        const float t = acc[mi][ni][r_] + bv[r_];
        vv[r_] = t >= 0.f ? t : 0.1f * t;
      }
      *(f32x4*)(out + (size_t)mm * OUTF + n) = vv;
    }
  }
}

extern "C" void kernel_launch(void* const* d_in, const int* in_sizes, int n_in,
                              void* d_out, int out_size, void* d_ws, size_t ws_size,
                              hipStream_t stream) {
  const float* x      = (const float*)d_in[0];
  const int*   bonded = (const int*)d_in[1];
  const float* Wih    = (const float*)d_in[2];
  const float* Whh    = (const float*)d_in[3];
  const float* bih    = (const float*)d_in[4];
  const float* bhh    = (const float*)d_in[5];
  const float* Wfc    = (const float*)d_in[6];
  const float* bfc    = (const float*)d_in[7];
  float* out = (float*)d_out;

  char* ws = (char*)d_ws;
  u16* xp2  = (u16*)(ws);                       // 50,331,648 B
  u16* rnn  = (u16*)(ws + 50331648);            // 16,777,216 B
  u16* whhb = (u16*)(ws + 67108864);            //    393,216 B
  u16* wfcb = (u16*)(ws + 67502080);            //    786,432 B

  k_xproj<<<dim3(256, 6), 256, 0, stream>>>(x, Wih, bih, bhh, xp2,
                                            Whh, whhb, Wfc, wfcb);
  k_gru<<<64, 256, 0, stream>>>(whhb, bhh, xp2, rnn);
  k_fc<<<dim3(256, 2), 256, 0, stream>>>(rnn, bonded, wfcb, bfc, out);
}